// Round 11
// baseline (956.513 us; speedup 1.0000x reference)
//
#include <hip/hip_runtime.h>
#include <math.h>

#define NB 20
#define SDIM 160   // 20*8
#define H1 64
#define TWO_PI_F 6.28318530717958647692f

// ws layout (floats), all rows float4-aligned
#define WS_DROW  0      // 64 density rows x 28: [w0..w23, beff, w2q, pad, pad]
#define WS_CROW  1792   // 64 color rows  x 32: [w0..w23, beff, wd, w2c0, w2c1, w2c2, pad x3]
#define WS_MISC  3840   // [0]=fq_b2, [1..3]=col_b2
#define WS_FLAG  3848   // two int flags (producer-consumer), both must match
#define FLAG_MAGIC0 0x13579BDF
#define FLAG_MAGIC1 0x2468ACE1

typedef float f2 __attribute__((ext_vector_type(2)));

__device__ __forceinline__ float fast_sigmoid(float x){ return 1.0f/(1.0f+__expf(-x)); }
__device__ __forceinline__ float fast_softplus(float x){
    return fmaxf(x, 0.0f) + __logf(1.0f + __expf(-fabsf(x)));
}
__device__ __forceinline__ float fast_rcp(float x){ return __builtin_amdgcn_rcpf(x); }
__device__ __forceinline__ float fast_rsq(float x){ return __builtin_amdgcn_rsqf(x); }
__device__ __forceinline__ float bperm(float v, int srcLane){
    return __int_as_float(__builtin_amdgcn_ds_bpermute(srcLane << 2, __float_as_int(v)));
}
__device__ __forceinline__ float rdlane(float v, int l){
    return __int_as_float(__builtin_amdgcn_readlane(__float_as_int(v), l));
}
__device__ __forceinline__ float getS(float s0, float s1, float s2, int f){
    return (f < 64) ? rdlane(s0, f) : (f < 128) ? rdlane(s1, f - 64) : rdlane(s2, f - 128);
}
__device__ __forceinline__ f2 pkfma(f2 a, f2 b, f2 c){
    return __builtin_elementwise_fma(a, b, c);
}

// ---------------------------------------------------------------------------
// Fused kernel, 512-thread blocks. Block 0: 8-wave VGPR-dieted sim
// (phase-1 K split 7 ways, wave 7 = forces; phase-2 K split 8 ways) -> pack
// ws -> release 64-bit magic. Blocks 1..: acquire-spin, then 1-pt/thread
// field eval. Low VGPR (~64-80) is the whole point: consumer occupancy.
// ---------------------------------------------------------------------------
__global__ __launch_bounds__(512) void fused_kernel(
    const float* __restrict__ p,
    const float* __restrict__ initial_state,
    const float* __restrict__ dyn_w1, const float* __restrict__ dyn_b1,
    const float* __restrict__ dyn_w2, const float* __restrict__ dyn_b2,
    const float* __restrict__ couplingP, const float* __restrict__ dampingP,
    const float* __restrict__ interaction,
    const float* __restrict__ summ_w, const float* __restrict__ summ_b,
    const float* __restrict__ fq_w1, const float* __restrict__ fq_b1,
    const float* __restrict__ fq_w2, const float* __restrict__ fq_b2,
    const float* __restrict__ col_w1, const float* __restrict__ col_b1,
    const float* __restrict__ col_w2, const float* __restrict__ col_b2,
    const int* __restrict__ tP,
    float* ws, float* out, int N)
{
    __shared__ float sP1L[64*8];     // phase-1 partials [j][wave], slot 7 zeroed
    __shared__ float sDnP[128*8];    // phase-2 partials [o][wave]
    __shared__ float sFr[64];        // forces [b*3+c]
    __shared__ float sPosL[64];      // positions [b*3+c], maintained by wave 7
    __shared__ float sSum[32];

    const int tid = threadIdx.x;

    if (blockIdx.x == 0){
        // =================== SIMULATION (block 0, 8 waves) ===================
        const int wv   = tid >> 6;          // 0..7
        const int lane = tid & 63;

        if (tid < 60) sPosL[tid] = initial_state[(tid/3)*8 + (tid - (tid/3)*3)];
        if (tid < 64) sP1L[tid*8 + 7] = 0.0f;   // wave 7 never writes phase-1
        __syncthreads();

        // ---- per-wave register weights ----
        // waves 0..6: W1 fragment (23 cols); wave 7: reuse w1s[0..6] as its
        // interaction row (no extra registers).
        const int fi  = lane % 20;
        const int jg  = lane / 20;
        const int jj0 = jg * 7;
        float w1s[23];
        if (wv < 7){
            const int kb = wv*23;
            #pragma unroll
            for (int t = 0; t < 23; ++t){
                int kk = kb + t; if (kk > 159) kk = 159;   // wv6 has 22 valid
                w1s[t] = dyn_w1[lane*SDIM + kk];
            }
        } else {
            #pragma unroll
            for (int u = 0; u < 7; ++u){
                int jj = jj0 + u;
                w1s[u] = (lane < 60 && jj < NB) ? interaction[fi*NB + jj] : 0.0f;
            }
            #pragma unroll
            for (int u = 7; u < 23; ++u) w1s[u] = 0.0f;
        }
        float w2a8[8], w2b8[8];
        {
            const int kb2 = wv*8;
            const int rowA = (lane/5)*8 + 3 + (lane - (lane/5)*5);
            const int o2   = 64 + lane;
            const int rowB = (o2 < 100) ? (o2/5)*8 + 3 + (o2 - (o2/5)*5) : 0;
            const bool vb  = (o2 < 100);
            #pragma unroll
            for (int t = 0; t < 8; ++t){
                w2a8[t] = dyn_w2[rowA*H1 + kb2 + t];
                w2b8[t] = vb ? dyn_w2[rowB*H1 + kb2 + t] : 0.0f;
            }
        }

        // ---- replicated state ----
        float s0 = initial_state[lane];
        float s1 = initial_state[64 + lane];
        float s2 = (lane < 32) ? initial_state[128 + lane] : 0.0f;

        const float b1r = dyn_b1[lane];
        float b2ar, b2br;
        { int b = lane/5, c = lane - (lane/5)*5; b2ar = dyn_b2[b*8 + 3 + c]; }
        { int o2 = 64 + lane;
          if (o2 < 100){ int b = o2/5, c = o2 - (o2/5)*5; b2br = dyn_b2[b*8 + 3 + c]; }
          else b2br = 0.0f; }
        const float bA0 = (wv == 0) ? b2ar : 0.0f;
        const float bB0 = (wv == 0) ? b2br : 0.0f;

        const float coupling = couplingP[0];
        const float damping  = dampingP[0];
        const int tv = tP[0];
        int n_steps = (int)((double)tv / 0.01);   // replicates Python int(t/DT): 2 -> 199
        if (n_steps < 1) n_steps = 1;
        const float adt = (float)((double)tv / (double)n_steps);

        const int cc  = lane & 7;
        const int bb  = lane >> 3;
        const int cm3 = (cc >= 3) ? cc - 3 : 0;
        const int lp3 = (lane + 3 > 63) ? 63 : lane + 3;

        for (int step = 0; step < n_steps; ++step){
            float fx = 0.f, fy = 0.f, fz = 0.f;
            if (wv < 7){
                // phase-1 partial: 23-wide K slice, constant lane indices
                float aa[4] = {0.f,0.f,0.f,0.f};
                if (wv == 0){
                    #pragma unroll
                    for (int t = 0; t < 23; ++t) aa[t&3] = fmaf(rdlane(s0, t), w1s[t], aa[t&3]);
                } else if (wv == 1){
                    #pragma unroll
                    for (int t = 0; t < 23; ++t) aa[t&3] = fmaf(rdlane(s0, 23+t), w1s[t], aa[t&3]);
                } else if (wv == 2){
                    #pragma unroll
                    for (int t = 0; t < 23; ++t){
                        float sv = (t < 18) ? rdlane(s0, 46+t) : rdlane(s1, t-18);
                        aa[t&3] = fmaf(sv, w1s[t], aa[t&3]);
                    }
                } else if (wv == 3){
                    #pragma unroll
                    for (int t = 0; t < 23; ++t) aa[t&3] = fmaf(rdlane(s1, 5+t), w1s[t], aa[t&3]);
                } else if (wv == 4){
                    #pragma unroll
                    for (int t = 0; t < 23; ++t) aa[t&3] = fmaf(rdlane(s1, 28+t), w1s[t], aa[t&3]);
                } else if (wv == 5){
                    #pragma unroll
                    for (int t = 0; t < 23; ++t){
                        float sv = (t < 13) ? rdlane(s1, 51+t) : rdlane(s2, t-13);
                        aa[t&3] = fmaf(sv, w1s[t], aa[t&3]);
                    }
                } else {
                    #pragma unroll
                    for (int t = 0; t < 22; ++t) aa[t&3] = fmaf(rdlane(s2, 10+t), w1s[t], aa[t&3]);
                }
                sP1L[lane*8 + wv] = (aa[0]+aa[1]) + (aa[2]+aa[3]);
            } else {
                // wave 7: forces (w1s[0..6] holds interaction row)
                float px = sPosL[fi*3+0], py = sPosL[fi*3+1], pz = sPosL[fi*3+2];
                #pragma unroll
                for (int u = 0; u < 7; ++u){
                    int jj = jj0 + u;
                    int js = (jj < NB) ? jj : 0;
                    float dx = px - sPosL[js*3+0];
                    float dy = py - sPosL[js*3+1];
                    float dz = pz - sPosL[js*3+2];
                    float e  = fmaf(dx,dx, fmaf(dy,dy, fmaf(dz,dz, 1e-6f)));
                    float d  = e * fast_rsq(e);
                    float mag = w1s[u] * fast_rcp(e + 1.0f);
                    float w   = mag * fast_rcp(d + 1e-6f);
                    fx = fmaf(dx, w, fx);
                    fy = fmaf(dy, w, fy);
                    fz = fmaf(dz, w, fz);
                }
                fx += bperm(fx, lane+20) + bperm(fx, lane+40);
                fy += bperm(fy, lane+20) + bperm(fy, lane+40);
                fz += bperm(fz, lane+20) + bperm(fz, lane+40);
            }

            __syncthreads();   // B1: phase-1 partials visible

            if (wv == 7 && lane < NB){
                sFr[lane*3+0] = fx; sFr[lane*3+1] = fy; sFr[lane*3+2] = fz;
            }

            // h assemble (all waves, redundant)
            float4 pa = *(const float4*)&sP1L[lane*8];
            float4 pb = *(const float4*)&sP1L[lane*8 + 4];
            float hv = ((pa.x+pa.y)+(pa.z+pa.w)) + ((pb.x+pb.y)+(pb.z+pb.w)) + b1r;
            hv = fminf(fmaxf(hv, -15.0f), 15.0f);
            float e2v = __expf(2.0f * hv);
            float hreg = (e2v - 1.0f) * fast_rcp(e2v + 1.0f);

            // phase-2 partial: 8-wide K slice
            {
                const int kb2 = wv*8;
                float dA0=0.f, dA1=0.f, dB0=0.f, dB1=0.f;
                #pragma unroll
                for (int t = 0; t < 8; t += 2){
                    float h0 = rdlane(hreg, kb2 + t);
                    float h1 = rdlane(hreg, kb2 + t + 1);
                    dA0 = fmaf(h0, w2a8[t],   dA0);
                    dA1 = fmaf(h1, w2a8[t+1], dA1);
                    dB0 = fmaf(h0, w2b8[t],   dB0);
                    dB1 = fmaf(h1, w2b8[t+1], dB1);
                }
                sDnP[lane*8 + wv]      = dA0 + dA1 + bA0;
                sDnP[(64+lane)*8 + wv] = dB0 + dB1 + bB0;
            }

            __syncthreads();   // B2: dn partials + forces visible

            {
                float v0 = bperm(s0, lp3);
                float v1 = bperm(s1, lp3);
                float v2 = bperm(s2, lp3);
                int o0 = bb*5 + cm3;
                int o1 = 40 + o0;
                int o2 = 80 + o0;
                float4 qa = *(const float4*)&sDnP[o0*8];
                float4 qb = *(const float4*)&sDnP[o0*8 + 4];
                float4 ra = *(const float4*)&sDnP[o1*8];
                float4 rb = *(const float4*)&sDnP[o1*8 + 4];
                float4 ta = *(const float4*)&sDnP[o2*8];
                float4 tb = *(const float4*)&sDnP[o2*8 + 4];
                float dn0 = ((qa.x+qa.y)+(qa.z+qa.w)) + ((qb.x+qb.y)+(qb.z+qb.w));
                float dn1 = ((ra.x+ra.y)+(ra.z+ra.w)) + ((rb.x+rb.y)+(rb.z+rb.w));
                float dn2 = ((ta.x+ta.y)+(ta.z+ta.w)) + ((tb.x+tb.y)+(tb.z+tb.w));
                float F0 = sFr[bb*3 + cm3];
                float F1 = sFr[(8+bb)*3 + cm3];
                float F2 = sFr[(lane < 32) ? (16+bb)*3 + cm3 : 0];

                float dv0 = (cc < 3) ? v0
                          : (cc < 6) ? fmaf(-damping, s0, fmaf(coupling, F0, dn0))
                          : (cc == 6) ? fmaf(-0.05f, s0 - 1.0f, dn0)
                                      : fmaf(-0.05f, s0 - 0.5f, dn0);
                float dv1 = (cc < 3) ? v1
                          : (cc < 6) ? fmaf(-damping, s1, fmaf(coupling, F1, dn1))
                          : (cc == 6) ? fmaf(-0.05f, s1 - 1.0f, dn1)
                                      : fmaf(-0.05f, s1 - 0.5f, dn1);
                float dv2 = (cc < 3) ? v2
                          : (cc < 6) ? fmaf(-damping, s2, fmaf(coupling, F2, dn2))
                          : (cc == 6) ? fmaf(-0.05f, s2 - 1.0f, dn2)
                                      : fmaf(-0.05f, s2 - 0.5f, dn2);

                s0 = fmaf(adt, dv0, s0);
                s1 = fmaf(adt, dv1, s1);
                s2 = fmaf(adt, dv2, s2);

                if (wv == 7 && cc < 3){   // only wave 7 reads sPosL
                    sPosL[bb*3 + cc]      = s0;
                    sPosL[(8+bb)*3 + cc]  = s1;
                    if (lane < 32) sPosL[(16+bb)*3 + cc] = s2;
                }
            }
        }

        if (wv == 0){
            // ---- summary = summ_w @ flat + summ_b ----
            {
                int sbase = (lane & 31) * SDIM;
                float sa = summ_b[lane & 31];
                #pragma unroll
                for (int k = 0; k < SDIM; ++k)
                    sa = fmaf(getS(s0,s1,s2,k), summ_w[sbase + k], sa);
                if (lane < 32) sSum[lane] = sa;
            }
            // ---- pack padded field-weight rows + effective biases ----
            {
                const int j = lane;
                int base = WS_DROW + j*28;
                #pragma unroll
                for (int k = 0; k < 24; ++k) ws[base + k] = fq_w1[j*56 + k];
                float bq = fq_b1[j];
                #pragma unroll
                for (int m = 0; m < 32; ++m) bq = fmaf(sSum[m], fq_w1[j*56 + 24 + m], bq);
                ws[base + 24] = bq;
                ws[base + 25] = fq_w2[j];
                ws[base + 26] = 0.0f;
                ws[base + 27] = 0.0f;
                base = WS_CROW + j*32;
                #pragma unroll
                for (int k = 0; k < 24; ++k) ws[base + k] = col_w1[j*57 + k];
                float bc = col_b1[j];
                #pragma unroll
                for (int m = 0; m < 32; ++m) bc = fmaf(sSum[m], col_w1[j*57 + 24 + m], bc);
                ws[base + 24] = bc;
                ws[base + 25] = col_w1[j*57 + 56];
                ws[base + 26] = col_w2[j];
                ws[base + 27] = col_w2[64 + j];
                ws[base + 28] = col_w2[128 + j];
                ws[base + 29] = 0.0f;
                ws[base + 30] = 0.0f;
                ws[base + 31] = 0.0f;
            }
            if (lane == 0){
                ws[WS_MISC + 0] = fq_b2[0];
                ws[WS_MISC + 1] = col_b2[0];
                ws[WS_MISC + 2] = col_b2[1];
                ws[WS_MISC + 3] = col_b2[2];
            }
        }
        __syncthreads();
        __threadfence();
        if (tid == 0){
            __hip_atomic_store((int*)(ws + WS_FLAG) + 1, FLAG_MAGIC1,
                               __ATOMIC_RELEASE, __HIP_MEMORY_SCOPE_AGENT);
            __hip_atomic_store((int*)(ws + WS_FLAG) + 0, FLAG_MAGIC0,
                               __ATOMIC_RELEASE, __HIP_MEMORY_SCOPE_AGENT);
        }
        return;
    }

    // ====================== FIELD EVAL (blocks 1..) ======================
    {
        const int* flagp = (const int*)(ws + WS_FLAG);
        if (tid == 0){
            for (;;){
                int f0 = __hip_atomic_load(flagp + 0, __ATOMIC_ACQUIRE, __HIP_MEMORY_SCOPE_AGENT);
                int f1 = __hip_atomic_load(flagp + 1, __ATOMIC_ACQUIRE, __HIP_MEMORY_SCOPE_AGENT);
                if (f0 == FLAG_MAGIC0 && f1 == FLAG_MAGIC1) break;
                __builtin_amdgcn_s_sleep(64);
            }
        }
        __syncthreads();
        (void)__hip_atomic_load(flagp, __ATOMIC_ACQUIRE, __HIP_MEMORY_SCOPE_AGENT);
    }

    const float m0  = ws[WS_MISC + 0];
    const float mc0 = ws[WS_MISC + 1];
    const float mc1 = ws[WS_MISC + 2];
    const float mc2 = ws[WS_MISC + 3];
    float* oc = out + N;

    const int nCons = (int)gridDim.x - 1;
    for (int base = ((int)blockIdx.x - 1) * 512; base < N; base += nCons * 512){
        const int i  = base + tid;
        const int li = (i < N) ? i : 0;

        f2 e[12];
        {
            const float a0 = p[3*li], a1 = p[3*li+1], a2 = p[3*li+2];
            float tA[24];
            #pragma unroll
            for (int f = 0; f < 4; ++f){
                const float w = TWO_PI_F * (float)(1 << f);
                float s, c;
                __sincosf(w * a0, &s, &c); tA[f*6+0] = s; tA[f*6+3] = c;
                __sincosf(w * a1, &s, &c); tA[f*6+1] = s; tA[f*6+4] = c;
                __sincosf(w * a2, &s, &c); tA[f*6+2] = s; tA[f*6+5] = c;
            }
            #pragma unroll
            for (int q = 0; q < 12; ++q) e[q] = (f2){tA[2*q], tA[2*q+1]};
        }

        // ---- density MLP ----
        float dA = m0;
        {
            const f2* R = (const f2*)(ws + WS_DROW);
            #pragma unroll 4
            for (int jj = 0; jj < 64; ++jj){
                const f2* r = R + jj*14;
                f2 a0 = {0.f,0.f}, a1 = {0.f,0.f};
                #pragma unroll
                for (int q = 0; q < 12; q += 2){
                    a0 = pkfma(e[q],   r[q],   a0);
                    a1 = pkfma(e[q+1], r[q+1], a1);
                }
                f2 m = r[12];
                f2 s2v = a0 + a1;
                float aA = fmaxf(s2v.x + s2v.y + m.x, 0.0f);
                dA = fmaf(aA, m.y, dA);
            }
        }
        const float dens = fast_softplus(dA);

        // ---- color MLP ----
        float c0 = mc0, c1 = mc1, c2 = mc2;
        {
            const f2* R = (const f2*)(ws + WS_CROW);
            #pragma unroll 4
            for (int jj = 0; jj < 64; ++jj){
                const f2* r = R + jj*16;
                f2 a0 = {0.f,0.f}, a1 = {0.f,0.f};
                #pragma unroll
                for (int q = 0; q < 12; q += 2){
                    a0 = pkfma(e[q],   r[q],   a0);
                    a1 = pkfma(e[q+1], r[q+1], a1);
                }
                f2 m   = r[12];
                f2 c01 = r[13];
                f2 c2p = r[14];
                f2 s2v = a0 + a1;
                float aA = s2v.x + s2v.y + m.x;
                aA = fmaxf(fmaf(dens, m.y, aA), 0.0f);
                c0 = fmaf(aA, c01.x, c0);
                c1 = fmaf(aA, c01.y, c1);
                c2 = fmaf(aA, c2p.x, c2);
            }
        }

        if (i < N){
            out[i] = dens;
            oc[3*i + 0] = fast_sigmoid(c0);
            oc[3*i + 1] = fast_sigmoid(c1);
            oc[3*i + 2] = fast_sigmoid(c2);
        }
    }
}

extern "C" void kernel_launch(void* const* d_in, const int* in_sizes, int n_in,
                              void* d_out, int out_size, void* d_ws, size_t ws_size,
                              hipStream_t stream)
{
    const float* p             = (const float*)d_in[0];
    const float* initial_state = (const float*)d_in[1];
    const float* dyn_w1        = (const float*)d_in[2];
    const float* dyn_b1        = (const float*)d_in[3];
    const float* dyn_w2        = (const float*)d_in[4];
    const float* dyn_b2        = (const float*)d_in[5];
    const float* coupling      = (const float*)d_in[6];
    const float* damping       = (const float*)d_in[7];
    const float* interaction   = (const float*)d_in[8];
    const float* summ_w        = (const float*)d_in[9];
    const float* summ_b        = (const float*)d_in[10];
    const float* fq_w1         = (const float*)d_in[11];
    const float* fq_b1         = (const float*)d_in[12];
    const float* fq_w2         = (const float*)d_in[13];
    const float* fq_b2         = (const float*)d_in[14];
    const float* col_w1        = (const float*)d_in[15];
    const float* col_b1        = (const float*)d_in[16];
    const float* col_w2        = (const float*)d_in[17];
    const float* col_b2        = (const float*)d_in[18];
    const int*   tP            = (const int*)d_in[19];

    float* ws  = (float*)d_ws;
    float* out = (float*)d_out;
    const int N = in_sizes[0] / 3;

    // Grid = co-resident capacity for THIS binary (conservative -> spin-safe).
    int blocksPerCU = 0;
    (void)hipOccupancyMaxActiveBlocksPerMultiprocessor(&blocksPerCU,
            (const void*)fused_kernel, 512, 0);
    if (blocksPerCU < 1) blocksPerCU = 1;
    int numCU = 0;
    (void)hipDeviceGetAttribute(&numCU, hipDeviceAttributeMultiprocessorCount, 0);
    if (numCU < 1) numCU = 256;
    long long grid = (long long)blocksPerCU * numCU;
    if (grid < 2) grid = 2;
    if (grid > 2048) grid = 2048;

    hipLaunchKernelGGL(fused_kernel, dim3((unsigned)grid), dim3(512), 0, stream,
                       p, initial_state, dyn_w1, dyn_b1, dyn_w2, dyn_b2,
                       coupling, damping, interaction, summ_w, summ_b,
                       fq_w1, fq_b1, fq_w2, fq_b2,
                       col_w1, col_b1, col_w2, col_b2, tP,
                       ws, out, N);
}

// Round 12
// 368.818 us; speedup vs baseline: 2.5935x; 2.5935x over previous
//
#include <hip/hip_runtime.h>
#include <math.h>

#define NB 20
#define SDIM 160   // 20*8
#define H1 64
#define TWO_PI_F 6.28318530717958647692f

// ws layout (floats), all rows float4-aligned
#define WS_DROW  0      // 64 density rows x 28: [w0..w23, beff, w2q, pad, pad]
#define WS_CROW  1792   // 64 color rows  x 32: [w0..w23, beff, wd, w2c0, w2c1, w2c2, pad x3]
#define WS_MISC  3840   // [0]=fq_b2, [1..3]=col_b2

typedef float f2 __attribute__((ext_vector_type(2)));

__device__ __forceinline__ float fast_sigmoid(float x){ return 1.0f/(1.0f+__expf(-x)); }
__device__ __forceinline__ float fast_softplus(float x){
    return fmaxf(x, 0.0f) + __logf(1.0f + __expf(-fabsf(x)));
}
__device__ __forceinline__ float fast_rcp(float x){ return __builtin_amdgcn_rcpf(x); }
__device__ __forceinline__ float fast_rsq(float x){ return __builtin_amdgcn_rsqf(x); }
__device__ __forceinline__ float bperm(float v, int srcLane){
    return __int_as_float(__builtin_amdgcn_ds_bpermute(srcLane << 2, __float_as_int(v)));
}
__device__ __forceinline__ float rdlane(float v, int l){
    return __int_as_float(__builtin_amdgcn_readlane(__float_as_int(v), l));
}
__device__ __forceinline__ float getS(float s0, float s1, float s2, int f){
    return (f < 64) ? rdlane(s0, f) : (f < 128) ? rdlane(s1, f - 64) : rdlane(s2, f - 128);
}
__device__ __forceinline__ f2 pkfma(f2 a, f2 b, f2 c){
    return __builtin_elementwise_fma(a, b, c);
}

// ---------------------------------------------------------------------------
// 4-wave blob simulation, standalone (two-kernel structure won: fusion rounds
// 7-11 all lost to the co-residency/occupancy cap).
// Deltas vs the 218us round-5 version:
//  - weights loaded direct from global (no 72KB LDS staging; proven identical)
//  - partials in [wave][idx] layout, scalar conflict-free reads (the old
//    [idx][wave] float4 reads were 8-way bank conflicts, 28038/dispatch)
// ---------------------------------------------------------------------------
__global__ __launch_bounds__(256, 1) void blob_sim_kernel(
    const float* __restrict__ initial_state,
    const float* __restrict__ dyn_w1, const float* __restrict__ dyn_b1,
    const float* __restrict__ dyn_w2, const float* __restrict__ dyn_b2,
    const float* __restrict__ couplingP, const float* __restrict__ dampingP,
    const float* __restrict__ interaction,
    const float* __restrict__ summ_w, const float* __restrict__ summ_b,
    const float* __restrict__ fq_w1, const float* __restrict__ fq_b1,
    const float* __restrict__ fq_w2, const float* __restrict__ fq_b2,
    const float* __restrict__ col_w1, const float* __restrict__ col_b1,
    const float* __restrict__ col_w2, const float* __restrict__ col_b2,
    const int* __restrict__ tP,
    float* __restrict__ ws)
{
    __shared__ float sP1L[3*64];     // phase-1 partials [wave][j], waves 0-2
    __shared__ float sDnP[4*128];    // phase-2 partials [wave][o]
    __shared__ float sFr[64];        // forces [b*3+c]
    __shared__ float sPosL[64];      // positions [b*3+c], maintained by wave 3
    __shared__ float sSum[32];

    const int tid  = threadIdx.x;
    const int wv   = tid >> 6;
    const int lane = tid & 63;

    if (tid < 60) sPosL[tid] = initial_state[(tid/3)*8 + (tid - (tid/3)*3)];
    __syncthreads();

    // ---- per-wave register weights, loaded straight from global ----
    float w1s[54];
    if (wv < 3){
        const int kb = wv*53;
        #pragma unroll
        for (int t2 = 0; t2 < 54; ++t2) w1s[t2] = dyn_w1[lane*SDIM + kb + t2];
    }
    float w2a16[16], w2b16[16];
    {
        const int kb2 = wv*16;
        const int rowA = (lane/5)*8 + 3 + (lane - (lane/5)*5);
        const int o2   = 64 + lane;
        const int rowB = (o2 < 100) ? (o2/5)*8 + 3 + (o2 - (o2/5)*5) : 0;
        const bool vb  = (o2 < 100);
        #pragma unroll
        for (int t2 = 0; t2 < 16; ++t2){
            w2a16[t2] = dyn_w2[rowA*H1 + kb2 + t2];
            w2b16[t2] = vb ? dyn_w2[rowB*H1 + kb2 + t2] : 0.0f;
        }
    }

    // wave-3 force decomposition: lane = jg*20 + fi, jj range [jg*7, jg*7+7)
    const int fi  = lane % 20;
    const int jg  = lane / 20;
    const int jj0 = jg * 7;
    float rintw[7];
    #pragma unroll
    for (int u = 0; u < 7; ++u){
        int jj = jj0 + u;
        rintw[u] = (wv == 3 && lane < 60 && jj < NB) ? interaction[fi*NB + jj] : 0.0f;
    }

    // ---- replicated state ----
    float s0 = initial_state[lane];
    float s1 = initial_state[64 + lane];
    float s2 = (lane < 32) ? initial_state[128 + lane] : 0.0f;

    const float b1r = dyn_b1[lane];
    float b2ar, b2br;
    { int b = lane/5, c = lane - (lane/5)*5; b2ar = dyn_b2[b*8 + 3 + c]; }
    { int o2 = 64 + lane;
      if (o2 < 100){ int b = o2/5, c = o2 - (o2/5)*5; b2br = dyn_b2[b*8 + 3 + c]; }
      else b2br = 0.0f; }
    const float bA0 = (wv == 0) ? b2ar : 0.0f;
    const float bB0 = (wv == 0) ? b2br : 0.0f;

    const float coupling = couplingP[0];
    const float damping  = dampingP[0];
    const int tv = tP[0];
    int n_steps = (int)((double)tv / 0.01);   // replicates Python int(t/DT): 2 -> 199
    if (n_steps < 1) n_steps = 1;
    const float adt = (float)((double)tv / (double)n_steps);

    const int cc  = lane & 7;
    const int bb  = lane >> 3;
    const int cm3 = (cc >= 3) ? cc - 3 : 0;
    const int lp3 = (lane + 3 > 63) ? 63 : lane + 3;

    for (int step = 0; step < n_steps; ++step){
        float fx = 0.f, fy = 0.f, fz = 0.f;
        if (wv < 3){
            float aa[4] = {0.f, 0.f, 0.f, 0.f};
            if (wv == 0){
                #pragma unroll
                for (int t2 = 0; t2 < 53; ++t2)
                    aa[t2&3] = fmaf(rdlane(s0, t2), w1s[t2], aa[t2&3]);
            } else if (wv == 1){
                #pragma unroll
                for (int t2 = 0; t2 < 53; ++t2){
                    int k = 53 + t2;
                    float sv = (k < 64) ? rdlane(s0, k) : rdlane(s1, k - 64);
                    aa[t2&3] = fmaf(sv, w1s[t2], aa[t2&3]);
                }
            } else {
                #pragma unroll
                for (int t2 = 0; t2 < 54; ++t2){
                    int k = 106 + t2;
                    float sv = (k < 128) ? rdlane(s1, k - 64) : rdlane(s2, k - 128);
                    aa[t2&3] = fmaf(sv, w1s[t2], aa[t2&3]);
                }
            }
            sP1L[wv*64 + lane] = (aa[0] + aa[1]) + (aa[2] + aa[3]);
        } else {
            float px = sPosL[fi*3+0], py = sPosL[fi*3+1], pz = sPosL[fi*3+2];
            #pragma unroll
            for (int u = 0; u < 7; ++u){
                int jj = jj0 + u;
                int js = (jj < NB) ? jj : 0;
                float dx = px - sPosL[js*3+0];
                float dy = py - sPosL[js*3+1];
                float dz = pz - sPosL[js*3+2];
                float e  = fmaf(dx,dx, fmaf(dy,dy, fmaf(dz,dz, 1e-6f)));
                float d  = e * fast_rsq(e);
                float mag = rintw[u] * fast_rcp(e + 1.0f);
                float w   = mag * fast_rcp(d + 1e-6f);
                fx = fmaf(dx, w, fx);
                fy = fmaf(dy, w, fy);
                fz = fmaf(dz, w, fz);
            }
            fx += bperm(fx, lane+20) + bperm(fx, lane+40);
            fy += bperm(fy, lane+20) + bperm(fy, lane+40);
            fz += bperm(fz, lane+20) + bperm(fz, lane+40);
        }

        __syncthreads();   // B1: phase-1 partials visible

        if (wv == 3 && lane < NB){
            sFr[lane*3+0] = fx; sFr[lane*3+1] = fy; sFr[lane*3+2] = fz;
        }

        // h assemble: 3 conflict-free stride-1 scalar reads
        float hv = (sP1L[lane] + sP1L[64 + lane]) + sP1L[128 + lane] + b1r;
        hv = fminf(fmaxf(hv, -15.0f), 15.0f);
        float e2v = __expf(2.0f * hv);
        float hreg = (e2v - 1.0f) * fast_rcp(e2v + 1.0f);

        {
            float dA0=0.f, dA1=0.f, dB0=0.f, dB1=0.f;
            const int kb2 = wv*16;
            #pragma unroll
            for (int t2 = 0; t2 < 16; t2 += 2){
                float h0 = rdlane(hreg, kb2 + t2);
                float h1 = rdlane(hreg, kb2 + t2 + 1);
                dA0 = fmaf(h0, w2a16[t2],   dA0);
                dA1 = fmaf(h1, w2a16[t2+1], dA1);
                dB0 = fmaf(h0, w2b16[t2],   dB0);
                dB1 = fmaf(h1, w2b16[t2+1], dB1);
            }
            sDnP[wv*128 + lane]      = dA0 + dA1 + bA0;
            sDnP[wv*128 + 64 + lane] = dB0 + dB1 + bB0;
        }

        __syncthreads();   // B2: dn partials + forces visible

        {
            float v0 = bperm(s0, lp3);
            float v1 = bperm(s1, lp3);
            float v2 = bperm(s2, lp3);
            int o0 = bb*5 + cm3;              // < 40
            int o1 = 40 + o0;                 // 40..79
            int o2 = 80 + o0;                 // 80..117, used only lane<32
            float dn0 = (sDnP[o0] + sDnP[128 + o0]) + (sDnP[256 + o0] + sDnP[384 + o0]);
            float dn1 = (sDnP[o1] + sDnP[128 + o1]) + (sDnP[256 + o1] + sDnP[384 + o1]);
            float dn2 = (sDnP[o2] + sDnP[128 + o2]) + (sDnP[256 + o2] + sDnP[384 + o2]);
            float F0 = sFr[bb*3 + cm3];
            float F1 = sFr[(8+bb)*3 + cm3];
            float F2 = sFr[(lane < 32) ? (16+bb)*3 + cm3 : 0];

            float dv0 = (cc < 3) ? v0
                      : (cc < 6) ? fmaf(-damping, s0, fmaf(coupling, F0, dn0))
                      : (cc == 6) ? fmaf(-0.05f, s0 - 1.0f, dn0)
                                  : fmaf(-0.05f, s0 - 0.5f, dn0);
            float dv1 = (cc < 3) ? v1
                      : (cc < 6) ? fmaf(-damping, s1, fmaf(coupling, F1, dn1))
                      : (cc == 6) ? fmaf(-0.05f, s1 - 1.0f, dn1)
                                  : fmaf(-0.05f, s1 - 0.5f, dn1);
            float dv2 = (cc < 3) ? v2
                      : (cc < 6) ? fmaf(-damping, s2, fmaf(coupling, F2, dn2))
                      : (cc == 6) ? fmaf(-0.05f, s2 - 1.0f, dn2)
                                  : fmaf(-0.05f, s2 - 0.5f, dn2);

            s0 = fmaf(adt, dv0, s0);
            s1 = fmaf(adt, dv1, s1);
            s2 = fmaf(adt, dv2, s2);

            if (wv == 3 && cc < 3){
                sPosL[bb*3 + cc]      = s0;
                sPosL[(8+bb)*3 + cc]  = s1;
                if (lane < 32) sPosL[(16+bb)*3 + cc] = s2;
            }
        }
    }

    if (wv != 0) return;   // tail on wave 0 only (no barriers below)

    // ---- summary = summ_w @ flat + summ_b ----
    {
        int sbase = (lane & 31) * SDIM;
        float sa = summ_b[lane & 31];
        #pragma unroll
        for (int k = 0; k < SDIM; ++k)
            sa = fmaf(getS(s0,s1,s2,k), summ_w[sbase + k], sa);
        if (lane < 32) sSum[lane] = sa;
    }

    // ---- pack padded field-weight rows; fold summary into effective biases ----
    {
        const int j = lane;
        int base = WS_DROW + j*28;
        #pragma unroll
        for (int k = 0; k < 24; ++k) ws[base + k] = fq_w1[j*56 + k];
        float bq = fq_b1[j];
        #pragma unroll
        for (int m = 0; m < 32; ++m) bq = fmaf(sSum[m], fq_w1[j*56 + 24 + m], bq);
        ws[base + 24] = bq;
        ws[base + 25] = fq_w2[j];
        ws[base + 26] = 0.0f;
        ws[base + 27] = 0.0f;
        base = WS_CROW + j*32;
        #pragma unroll
        for (int k = 0; k < 24; ++k) ws[base + k] = col_w1[j*57 + k];
        float bc = col_b1[j];
        #pragma unroll
        for (int m = 0; m < 32; ++m) bc = fmaf(sSum[m], col_w1[j*57 + 24 + m], bc);
        ws[base + 24] = bc;
        ws[base + 25] = col_w1[j*57 + 56];
        ws[base + 26] = col_w2[j];
        ws[base + 27] = col_w2[64 + j];
        ws[base + 28] = col_w2[128 + j];
        ws[base + 29] = 0.0f;
        ws[base + 30] = 0.0f;
        ws[base + 31] = 0.0f;
    }
    if (lane == 0){
        ws[WS_MISC + 0] = fq_b2[0];
        ws[WS_MISC + 1] = col_b2[0];
        ws[WS_MISC + 2] = col_b2[1];
        ws[WS_MISC + 3] = col_b2[2];
    }
}

// ---------------------------------------------------------------------------
// Field eval: exact round-6 kernel (measured ~148us, 94% VALUBusy).
// 2 points per thread, f2 packed dots, uniform ws -> SMEM weight flow.
// ---------------------------------------------------------------------------
__global__ __launch_bounds__(256) void field_kernel(
    const float* __restrict__ p,
    const float* __restrict__ ws,
    float* __restrict__ out, int N)
{
    const int tid = threadIdx.x;
    const int iA  = blockIdx.x * 512 + tid;
    const int iB  = iA + 256;
    const int lA  = (iA < N) ? iA : 0;
    const int lB  = (iB < N) ? iB : 0;

    f2 eA[12], eB[12];
    {
        const float a0 = p[3*lA], a1 = p[3*lA+1], a2 = p[3*lA+2];
        const float b0 = p[3*lB], b1 = p[3*lB+1], b2 = p[3*lB+2];
        float tA[24], tB[24];
        #pragma unroll
        for (int f = 0; f < 4; ++f){
            const float w = TWO_PI_F * (float)(1 << f);
            float s, c;
            __sincosf(w * a0, &s, &c); tA[f*6+0] = s; tA[f*6+3] = c;
            __sincosf(w * a1, &s, &c); tA[f*6+1] = s; tA[f*6+4] = c;
            __sincosf(w * a2, &s, &c); tA[f*6+2] = s; tA[f*6+5] = c;
            __sincosf(w * b0, &s, &c); tB[f*6+0] = s; tB[f*6+3] = c;
            __sincosf(w * b1, &s, &c); tB[f*6+1] = s; tB[f*6+4] = c;
            __sincosf(w * b2, &s, &c); tB[f*6+2] = s; tB[f*6+5] = c;
        }
        #pragma unroll
        for (int q = 0; q < 12; ++q){
            eA[q] = (f2){tA[2*q], tA[2*q+1]};
            eB[q] = (f2){tB[2*q], tB[2*q+1]};
        }
    }

    const float m0  = ws[WS_MISC + 0];
    const float mc0 = ws[WS_MISC + 1];
    const float mc1 = ws[WS_MISC + 2];
    const float mc2 = ws[WS_MISC + 3];

    // ---- density MLP ----
    float dA = m0, dB = m0;
    {
        const f2* R = (const f2*)(ws + WS_DROW);
        #pragma unroll 4
        for (int jj = 0; jj < 64; ++jj){
            const f2* r = R + jj*14;
            f2 aA0 = {0.f,0.f}, aA1 = {0.f,0.f};
            f2 aB0 = {0.f,0.f}, aB1 = {0.f,0.f};
            #pragma unroll
            for (int q = 0; q < 12; q += 2){
                f2 w0 = r[q], w1 = r[q+1];
                aA0 = pkfma(eA[q],   w0, aA0);
                aA1 = pkfma(eA[q+1], w1, aA1);
                aB0 = pkfma(eB[q],   w0, aB0);
                aB1 = pkfma(eB[q+1], w1, aB1);
            }
            f2 m = r[12];
            f2 sA2 = aA0 + aA1, sB2 = aB0 + aB1;
            float aA = fmaxf(sA2.x + sA2.y + m.x, 0.0f);
            float aB = fmaxf(sB2.x + sB2.y + m.x, 0.0f);
            dA = fmaf(aA, m.y, dA);
            dB = fmaf(aB, m.y, dB);
        }
    }
    const float densA = fast_softplus(dA);
    const float densB = fast_softplus(dB);

    // ---- color MLP ----
    float cA0 = mc0, cA1 = mc1, cA2 = mc2;
    float cB0 = mc0, cB1 = mc1, cB2 = mc2;
    {
        const f2* R = (const f2*)(ws + WS_CROW);
        #pragma unroll 4
        for (int jj = 0; jj < 64; ++jj){
            const f2* r = R + jj*16;
            f2 aA0 = {0.f,0.f}, aA1 = {0.f,0.f};
            f2 aB0 = {0.f,0.f}, aB1 = {0.f,0.f};
            #pragma unroll
            for (int q = 0; q < 12; q += 2){
                f2 w0 = r[q], w1 = r[q+1];
                aA0 = pkfma(eA[q],   w0, aA0);
                aA1 = pkfma(eA[q+1], w1, aA1);
                aB0 = pkfma(eB[q],   w0, aB0);
                aB1 = pkfma(eB[q+1], w1, aB1);
            }
            f2 m  = r[12];
            f2 c01 = r[13];
            f2 c2p = r[14];
            f2 sA2 = aA0 + aA1, sB2 = aB0 + aB1;
            float aA = sA2.x + sA2.y + m.x;
            float aB = sB2.x + sB2.y + m.x;
            aA = fmaxf(fmaf(densA, m.y, aA), 0.0f);
            aB = fmaxf(fmaf(densB, m.y, aB), 0.0f);
            cA0 = fmaf(aA, c01.x, cA0); cA1 = fmaf(aA, c01.y, cA1); cA2 = fmaf(aA, c2p.x, cA2);
            cB0 = fmaf(aB, c01.x, cB0); cB1 = fmaf(aB, c01.y, cB1); cB2 = fmaf(aB, c2p.x, cB2);
        }
    }

    float* oc = out + N;
    if (iA < N){
        out[iA] = densA;
        oc[3*iA + 0] = fast_sigmoid(cA0);
        oc[3*iA + 1] = fast_sigmoid(cA1);
        oc[3*iA + 2] = fast_sigmoid(cA2);
    }
    if (iB < N){
        out[iB] = densB;
        oc[3*iB + 0] = fast_sigmoid(cB0);
        oc[3*iB + 1] = fast_sigmoid(cB1);
        oc[3*iB + 2] = fast_sigmoid(cB2);
    }
}

extern "C" void kernel_launch(void* const* d_in, const int* in_sizes, int n_in,
                              void* d_out, int out_size, void* d_ws, size_t ws_size,
                              hipStream_t stream)
{
    const float* p             = (const float*)d_in[0];
    const float* initial_state = (const float*)d_in[1];
    const float* dyn_w1        = (const float*)d_in[2];
    const float* dyn_b1        = (const float*)d_in[3];
    const float* dyn_w2        = (const float*)d_in[4];
    const float* dyn_b2        = (const float*)d_in[5];
    const float* coupling      = (const float*)d_in[6];
    const float* damping       = (const float*)d_in[7];
    const float* interaction   = (const float*)d_in[8];
    const float* summ_w        = (const float*)d_in[9];
    const float* summ_b        = (const float*)d_in[10];
    const float* fq_w1         = (const float*)d_in[11];
    const float* fq_b1         = (const float*)d_in[12];
    const float* fq_w2         = (const float*)d_in[13];
    const float* fq_b2         = (const float*)d_in[14];
    const float* col_w1        = (const float*)d_in[15];
    const float* col_b1        = (const float*)d_in[16];
    const float* col_w2        = (const float*)d_in[17];
    const float* col_b2        = (const float*)d_in[18];
    const int*   tP            = (const int*)d_in[19];

    float* ws  = (float*)d_ws;
    float* out = (float*)d_out;
    const int N = in_sizes[0] / 3;

    hipLaunchKernelGGL(blob_sim_kernel, dim3(1), dim3(256), 0, stream,
                       initial_state, dyn_w1, dyn_b1, dyn_w2, dyn_b2,
                       coupling, damping, interaction, summ_w, summ_b,
                       fq_w1, fq_b1, fq_w2, fq_b2,
                       col_w1, col_b1, col_w2, col_b2, tP, ws);

    const int blocks = (N + 511) / 512;
    hipLaunchKernelGGL(field_kernel, dim3(blocks), dim3(256), 0, stream,
                       p, ws, out, N);
}

// Round 13
// 340.994 us; speedup vs baseline: 2.8051x; 1.0816x over previous
//
#include <hip/hip_runtime.h>
#include <math.h>

#define NB 20
#define SDIM 160   // 20*8
#define H1 64
#define TWO_PI_F 6.28318530717958647692f

// ws layout (dword offsets)
#define WS_DFRAG 0      // density W frags: [u][half][lane] uint4 -> 2048 dw
#define WS_CFRAG 2048   // color   W frags: 2048 dw
#define WS_DBEFF 4096   // [64] f32 density effective bias (b + summary fold)
#define WS_DW2   4160   // [64] fq_w2
#define WS_CBEFF 4224   // [64] color effective bias
#define WS_WD    4288   // [64] col_w1[:,56] (density weight)
#define WS_W2C0  4352   // [64]
#define WS_W2C1  4416
#define WS_W2C2  4480
#define WS_MISC2 4544   // [0]=fq_b2, [1..3]=col_b2

typedef short  bf16x8 __attribute__((ext_vector_type(8)));
typedef float  f32x4  __attribute__((ext_vector_type(4)));

__device__ __forceinline__ float fast_sigmoid(float x){ return 1.0f/(1.0f+__expf(-x)); }
__device__ __forceinline__ float fast_softplus(float x){
    return fmaxf(x, 0.0f) + __logf(1.0f + __expf(-fabsf(x)));
}
__device__ __forceinline__ float fast_rcp(float x){ return __builtin_amdgcn_rcpf(x); }
__device__ __forceinline__ float fast_rsq(float x){ return __builtin_amdgcn_rsqf(x); }
__device__ __forceinline__ float bperm(float v, int srcLane){
    return __int_as_float(__builtin_amdgcn_ds_bpermute(srcLane << 2, __float_as_int(v)));
}
__device__ __forceinline__ float rdlane(float v, int l){
    return __int_as_float(__builtin_amdgcn_readlane(__float_as_int(v), l));
}
__device__ __forceinline__ float getS(float s0, float s1, float s2, int f){
    return (f < 64) ? rdlane(s0, f) : (f < 128) ? rdlane(s1, f - 64) : rdlane(s2, f - 128);
}
__device__ __forceinline__ unsigned short bf16rn(float f){
    unsigned int u = __float_as_uint(f);
    unsigned int r = u + 0x7FFFu + ((u >> 16) & 1u);
    return (unsigned short)(r >> 16);
}
__device__ __forceinline__ float bf16tof(unsigned short h){
    return __uint_as_float(((unsigned int)h) << 16);
}
__device__ __forceinline__ f32x4 mfma_bf16(uint4 a, uint4 b, f32x4 c){
    return __builtin_amdgcn_mfma_f32_16x16x32_bf16(
        __builtin_bit_cast(bf16x8, a), __builtin_bit_cast(bf16x8, b), c, 0, 0, 0);
}

// ---------------------------------------------------------------------------
// 4-wave blob simulation (round-12 version; 215us) + MFMA-fragment ws prep.
// ---------------------------------------------------------------------------
__global__ __launch_bounds__(256, 1) void blob_sim_kernel(
    const float* __restrict__ initial_state,
    const float* __restrict__ dyn_w1, const float* __restrict__ dyn_b1,
    const float* __restrict__ dyn_w2, const float* __restrict__ dyn_b2,
    const float* __restrict__ couplingP, const float* __restrict__ dampingP,
    const float* __restrict__ interaction,
    const float* __restrict__ summ_w, const float* __restrict__ summ_b,
    const float* __restrict__ fq_w1, const float* __restrict__ fq_b1,
    const float* __restrict__ fq_w2, const float* __restrict__ fq_b2,
    const float* __restrict__ col_w1, const float* __restrict__ col_b1,
    const float* __restrict__ col_w2, const float* __restrict__ col_b2,
    const int* __restrict__ tP,
    float* __restrict__ ws)
{
    __shared__ float sP1L[3*64];     // phase-1 partials [wave][j]
    __shared__ float sDnP[4*128];    // phase-2 partials [wave][o]
    __shared__ float sFr[64];
    __shared__ float sPosL[64];
    __shared__ float sSum[32];

    const int tid  = threadIdx.x;
    const int wv   = tid >> 6;
    const int lane = tid & 63;

    if (tid < 60) sPosL[tid] = initial_state[(tid/3)*8 + (tid - (tid/3)*3)];
    __syncthreads();

    float w1s[54];
    if (wv < 3){
        const int kb = wv*53;
        #pragma unroll
        for (int t2 = 0; t2 < 54; ++t2) w1s[t2] = dyn_w1[lane*SDIM + kb + t2];
    }
    float w2a16[16], w2b16[16];
    {
        const int kb2 = wv*16;
        const int rowA = (lane/5)*8 + 3 + (lane - (lane/5)*5);
        const int o2   = 64 + lane;
        const int rowB = (o2 < 100) ? (o2/5)*8 + 3 + (o2 - (o2/5)*5) : 0;
        const bool vb  = (o2 < 100);
        #pragma unroll
        for (int t2 = 0; t2 < 16; ++t2){
            w2a16[t2] = dyn_w2[rowA*H1 + kb2 + t2];
            w2b16[t2] = vb ? dyn_w2[rowB*H1 + kb2 + t2] : 0.0f;
        }
    }

    const int fi  = lane % 20;
    const int jg  = lane / 20;
    const int jj0 = jg * 7;
    float rintw[7];
    #pragma unroll
    for (int u = 0; u < 7; ++u){
        int jj = jj0 + u;
        rintw[u] = (wv == 3 && lane < 60 && jj < NB) ? interaction[fi*NB + jj] : 0.0f;
    }

    float s0 = initial_state[lane];
    float s1 = initial_state[64 + lane];
    float s2 = (lane < 32) ? initial_state[128 + lane] : 0.0f;

    const float b1r = dyn_b1[lane];
    float b2ar, b2br;
    { int b = lane/5, c = lane - (lane/5)*5; b2ar = dyn_b2[b*8 + 3 + c]; }
    { int o2 = 64 + lane;
      if (o2 < 100){ int b = o2/5, c = o2 - (o2/5)*5; b2br = dyn_b2[b*8 + 3 + c]; }
      else b2br = 0.0f; }
    const float bA0 = (wv == 0) ? b2ar : 0.0f;
    const float bB0 = (wv == 0) ? b2br : 0.0f;

    const float coupling = couplingP[0];
    const float damping  = dampingP[0];
    const int tv = tP[0];
    int n_steps = (int)((double)tv / 0.01);   // replicates Python int(t/DT): 2 -> 199
    if (n_steps < 1) n_steps = 1;
    const float adt = (float)((double)tv / (double)n_steps);

    const int cc  = lane & 7;
    const int bb  = lane >> 3;
    const int cm3 = (cc >= 3) ? cc - 3 : 0;
    const int lp3 = (lane + 3 > 63) ? 63 : lane + 3;

    for (int step = 0; step < n_steps; ++step){
        float fx = 0.f, fy = 0.f, fz = 0.f;
        if (wv < 3){
            float aa[4] = {0.f, 0.f, 0.f, 0.f};
            if (wv == 0){
                #pragma unroll
                for (int t2 = 0; t2 < 53; ++t2)
                    aa[t2&3] = fmaf(rdlane(s0, t2), w1s[t2], aa[t2&3]);
            } else if (wv == 1){
                #pragma unroll
                for (int t2 = 0; t2 < 53; ++t2){
                    int k = 53 + t2;
                    float sv = (k < 64) ? rdlane(s0, k) : rdlane(s1, k - 64);
                    aa[t2&3] = fmaf(sv, w1s[t2], aa[t2&3]);
                }
            } else {
                #pragma unroll
                for (int t2 = 0; t2 < 54; ++t2){
                    int k = 106 + t2;
                    float sv = (k < 128) ? rdlane(s1, k - 64) : rdlane(s2, k - 128);
                    aa[t2&3] = fmaf(sv, w1s[t2], aa[t2&3]);
                }
            }
            sP1L[wv*64 + lane] = (aa[0] + aa[1]) + (aa[2] + aa[3]);
        } else {
            float px = sPosL[fi*3+0], py = sPosL[fi*3+1], pz = sPosL[fi*3+2];
            #pragma unroll
            for (int u = 0; u < 7; ++u){
                int jj = jj0 + u;
                int js = (jj < NB) ? jj : 0;
                float dx = px - sPosL[js*3+0];
                float dy = py - sPosL[js*3+1];
                float dz = pz - sPosL[js*3+2];
                float e  = fmaf(dx,dx, fmaf(dy,dy, fmaf(dz,dz, 1e-6f)));
                float d  = e * fast_rsq(e);
                float mag = rintw[u] * fast_rcp(e + 1.0f);
                float w   = mag * fast_rcp(d + 1e-6f);
                fx = fmaf(dx, w, fx);
                fy = fmaf(dy, w, fy);
                fz = fmaf(dz, w, fz);
            }
            fx += bperm(fx, lane+20) + bperm(fx, lane+40);
            fy += bperm(fy, lane+20) + bperm(fy, lane+40);
            fz += bperm(fz, lane+20) + bperm(fz, lane+40);
        }

        __syncthreads();   // B1

        if (wv == 3 && lane < NB){
            sFr[lane*3+0] = fx; sFr[lane*3+1] = fy; sFr[lane*3+2] = fz;
        }

        float hv = (sP1L[lane] + sP1L[64 + lane]) + sP1L[128 + lane] + b1r;
        hv = fminf(fmaxf(hv, -15.0f), 15.0f);
        float e2v = __expf(2.0f * hv);
        float hreg = (e2v - 1.0f) * fast_rcp(e2v + 1.0f);

        {
            float dA0=0.f, dA1=0.f, dB0=0.f, dB1=0.f;
            const int kb2 = wv*16;
            #pragma unroll
            for (int t2 = 0; t2 < 16; t2 += 2){
                float h0 = rdlane(hreg, kb2 + t2);
                float h1 = rdlane(hreg, kb2 + t2 + 1);
                dA0 = fmaf(h0, w2a16[t2],   dA0);
                dA1 = fmaf(h1, w2a16[t2+1], dA1);
                dB0 = fmaf(h0, w2b16[t2],   dB0);
                dB1 = fmaf(h1, w2b16[t2+1], dB1);
            }
            sDnP[wv*128 + lane]      = dA0 + dA1 + bA0;
            sDnP[wv*128 + 64 + lane] = dB0 + dB1 + bB0;
        }

        __syncthreads();   // B2

        {
            float v0 = bperm(s0, lp3);
            float v1 = bperm(s1, lp3);
            float v2 = bperm(s2, lp3);
            int o0 = bb*5 + cm3;
            int o1 = 40 + o0;
            int o2 = 80 + o0;
            float dn0 = (sDnP[o0] + sDnP[128 + o0]) + (sDnP[256 + o0] + sDnP[384 + o0]);
            float dn1 = (sDnP[o1] + sDnP[128 + o1]) + (sDnP[256 + o1] + sDnP[384 + o1]);
            float dn2 = (sDnP[o2] + sDnP[128 + o2]) + (sDnP[256 + o2] + sDnP[384 + o2]);
            float F0 = sFr[bb*3 + cm3];
            float F1 = sFr[(8+bb)*3 + cm3];
            float F2 = sFr[(lane < 32) ? (16+bb)*3 + cm3 : 0];

            float dv0 = (cc < 3) ? v0
                      : (cc < 6) ? fmaf(-damping, s0, fmaf(coupling, F0, dn0))
                      : (cc == 6) ? fmaf(-0.05f, s0 - 1.0f, dn0)
                                  : fmaf(-0.05f, s0 - 0.5f, dn0);
            float dv1 = (cc < 3) ? v1
                      : (cc < 6) ? fmaf(-damping, s1, fmaf(coupling, F1, dn1))
                      : (cc == 6) ? fmaf(-0.05f, s1 - 1.0f, dn1)
                                  : fmaf(-0.05f, s1 - 0.5f, dn1);
            float dv2 = (cc < 3) ? v2
                      : (cc < 6) ? fmaf(-damping, s2, fmaf(coupling, F2, dn2))
                      : (cc == 6) ? fmaf(-0.05f, s2 - 1.0f, dn2)
                                  : fmaf(-0.05f, s2 - 0.5f, dn2);

            s0 = fmaf(adt, dv0, s0);
            s1 = fmaf(adt, dv1, s1);
            s2 = fmaf(adt, dv2, s2);

            if (wv == 3 && cc < 3){
                sPosL[bb*3 + cc]      = s0;
                sPosL[(8+bb)*3 + cc]  = s1;
                if (lane < 32) sPosL[(16+bb)*3 + cc] = s2;
            }
        }
    }

    if (wv != 0) return;   // tail on wave 0 only

    // ---- summary ----
    {
        int sbase = (lane & 31) * SDIM;
        float sa = summ_b[lane & 31];
        #pragma unroll
        for (int k = 0; k < SDIM; ++k)
            sa = fmaf(getS(s0,s1,s2,k), summ_w[sbase + k], sa);
        if (lane < 32) sSum[lane] = sa;
    }

    // ---- effective biases + epilogue vectors (neuron j = lane) ----
    {
        float bq = fq_b1[lane], bc = col_b1[lane];
        #pragma unroll
        for (int m = 0; m < 32; ++m){
            bq = fmaf(sSum[m], fq_w1[lane*56 + 24 + m], bq);
            bc = fmaf(sSum[m], col_w1[lane*57 + 24 + m], bc);
        }
        ws[WS_DBEFF + lane] = bq;
        ws[WS_DW2   + lane] = fq_w2[lane];
        ws[WS_CBEFF + lane] = bc;
        ws[WS_WD    + lane] = col_w1[lane*57 + 56];
        ws[WS_W2C0  + lane] = col_w2[lane];
        ws[WS_W2C1  + lane] = col_w2[64 + lane];
        ws[WS_W2C2  + lane] = col_w2[128 + lane];
    }
    if (lane == 0){
        ws[WS_MISC2 + 0] = fq_b2[0];
        ws[WS_MISC2 + 1] = col_b2[0];
        ws[WS_MISC2 + 2] = col_b2[1];
        ws[WS_MISC2 + 3] = col_b2[2];
    }

    // ---- bf16 hi/lo B-fragments for MFMA field ----
    // B[k][n]: lane holds k = (lane>>4)*8 + j (j=0..7), n = u*16 + (lane&15).
    {
        unsigned int* wsu = (unsigned int*)ws;
        const int colc = lane & 15;
        const int kg   = lane >> 4;
        #pragma unroll
        for (int u = 0; u < 4; ++u){
            const int n = u*16 + colc;
            unsigned int hd[4], ldv[4], hc[4], lc[4];
            #pragma unroll
            for (int d = 0; d < 4; ++d){
                unsigned short hh[2], hl[2], ch[2], cl[2];
                #pragma unroll
                for (int e = 0; e < 2; ++e){
                    const int k = kg*8 + d*2 + e;
                    float wd_ = (k < 24) ? fq_w1[n*56 + k]  : 0.0f;
                    float wc_ = (k < 24) ? col_w1[n*57 + k] : 0.0f;
                    hh[e] = bf16rn(wd_); hl[e] = bf16rn(wd_ - bf16tof(hh[e]));
                    ch[e] = bf16rn(wc_); cl[e] = bf16rn(wc_ - bf16tof(ch[e]));
                }
                hd[d]  = (unsigned int)hh[0] | ((unsigned int)hh[1] << 16);
                ldv[d] = (unsigned int)hl[0] | ((unsigned int)hl[1] << 16);
                hc[d]  = (unsigned int)ch[0] | ((unsigned int)ch[1] << 16);
                lc[d]  = (unsigned int)cl[0] | ((unsigned int)cl[1] << 16);
            }
            *(uint4*)(wsu + WS_DFRAG + ((u*2+0)*64 + lane)*4) = make_uint4(hd[0],hd[1],hd[2],hd[3]);
            *(uint4*)(wsu + WS_DFRAG + ((u*2+1)*64 + lane)*4) = make_uint4(ldv[0],ldv[1],ldv[2],ldv[3]);
            *(uint4*)(wsu + WS_CFRAG + ((u*2+0)*64 + lane)*4) = make_uint4(hc[0],hc[1],hc[2],hc[3]);
            *(uint4*)(wsu + WS_CFRAG + ((u*2+1)*64 + lane)*4) = make_uint4(lc[0],lc[1],lc[2],lc[3]);
        }
    }
}

// ---------------------------------------------------------------------------
// MFMA field eval. Per wave: 64 points, penc -> bf16 hi/lo rows in per-wave
// LDS (stride 20 dw), A-frags via ds_read_b128, layer-1 dots on matrix cores
// (3-term compensated bf16), layer-2 + activations on VALU with shfl_xor
// butterfly over the 16 neuron columns. No barriers (same-wave LDS is
// in-order).
// ---------------------------------------------------------------------------
__global__ __launch_bounds__(256) void field_kernel(
    const float* __restrict__ p,
    const float* __restrict__ ws,
    float* __restrict__ out, int N)
{
    __shared__ unsigned int ldsA[2*4*1280];   // [half][wave][row*20] = 40KB

    const int tid  = threadIdx.x;
    const int w    = tid >> 6;
    const int lane = tid & 63;
    const int base = blockIdx.x * 256 + w * 64;
    int i = base + lane; if (i >= N) i = N - 1;

    // ---- penc (f32) ----
    float t24[24];
    {
        const float a0 = p[3*i], a1 = p[3*i+1], a2 = p[3*i+2];
        #pragma unroll
        for (int f = 0; f < 4; ++f){
            const float wf = TWO_PI_F * (float)(1 << f);
            float s, c;
            __sincosf(wf * a0, &s, &c); t24[f*6+0]=s; t24[f*6+3]=c;
            __sincosf(wf * a1, &s, &c); t24[f*6+1]=s; t24[f*6+4]=c;
            __sincosf(wf * a2, &s, &c); t24[f*6+2]=s; t24[f*6+5]=c;
        }
    }
    // ---- hi/lo split + pack, write own LDS row ----
    unsigned int hiR[16], loR[16];
    #pragma unroll
    for (int q = 0; q < 12; ++q){
        unsigned short h0 = bf16rn(t24[2*q]);
        unsigned short h1 = bf16rn(t24[2*q+1]);
        unsigned short l0 = bf16rn(t24[2*q]   - bf16tof(h0));
        unsigned short l1 = bf16rn(t24[2*q+1] - bf16tof(h1));
        hiR[q] = (unsigned int)h0 | ((unsigned int)h1 << 16);
        loR[q] = (unsigned int)l0 | ((unsigned int)l1 << 16);
    }
    #pragma unroll
    for (int q = 12; q < 16; ++q){ hiR[q] = 0u; loR[q] = 0u; }

    unsigned int* AhW = &ldsA[(0*4 + w)*1280];
    unsigned int* AlW = &ldsA[(1*4 + w)*1280];
    #pragma unroll
    for (int d = 0; d < 4; ++d){
        *(uint4*)(AhW + lane*20 + d*4) = make_uint4(hiR[d*4],hiR[d*4+1],hiR[d*4+2],hiR[d*4+3]);
        *(uint4*)(AlW + lane*20 + d*4) = make_uint4(loR[d*4],loR[d*4+1],loR[d*4+2],loR[d*4+3]);
    }

    // ---- A-fragment reads (row = t*16 + (lane&15), k-group = lane>>4) ----
    const int arow = lane & 15;
    const int aoff = (lane >> 4) * 4;
    uint4 Ah[4], Al[4];
    #pragma unroll
    for (int t = 0; t < 4; ++t){
        Ah[t] = *(const uint4*)(AhW + (t*16 + arow)*20 + aoff);
        Al[t] = *(const uint4*)(AlW + (t*16 + arow)*20 + aoff);
    }

    const unsigned int* wsu = (const unsigned int*)ws;
    const int ncol = lane & 15;

    // ---- density layer (MFMA) + layer-2 accumulate ----
    float sd[4][4];
    #pragma unroll
    for (int t = 0; t < 4; ++t){ sd[t][0]=0.f; sd[t][1]=0.f; sd[t][2]=0.f; sd[t][3]=0.f; }
    #pragma unroll
    for (int u = 0; u < 4; ++u){
        uint4 Bh = *(const uint4*)(wsu + WS_DFRAG + ((u*2+0)*64 + lane)*4);
        uint4 Bl = *(const uint4*)(wsu + WS_DFRAG + ((u*2+1)*64 + lane)*4);
        float beff = ws[WS_DBEFF + u*16 + ncol];
        float w2   = ws[WS_DW2   + u*16 + ncol];
        #pragma unroll
        for (int t = 0; t < 4; ++t){
            f32x4 acc = {0.f,0.f,0.f,0.f};
            acc = mfma_bf16(Ah[t], Bh, acc);
            acc = mfma_bf16(Ah[t], Bl, acc);
            acc = mfma_bf16(Al[t], Bh, acc);
            #pragma unroll
            for (int r = 0; r < 4; ++r){
                float v = fmaxf(acc[r] + beff, 0.0f);
                sd[t][r] = fmaf(v, w2, sd[t][r]);
            }
        }
    }
    // butterfly over neuron columns (lane&15)
    #pragma unroll
    for (int m = 1; m < 16; m <<= 1){
        #pragma unroll
        for (int t = 0; t < 4; ++t)
        #pragma unroll
        for (int r = 0; r < 4; ++r)
            sd[t][r] += __shfl_xor(sd[t][r], m, 64);
    }
    const float m0 = ws[WS_MISC2 + 0];
    float dens[4][4];
    #pragma unroll
    for (int t = 0; t < 4; ++t)
    #pragma unroll
    for (int r = 0; r < 4; ++r)
        dens[t][r] = fast_softplus(sd[t][r] + m0);

    // ---- color layer ----
    float c0s[4][4], c1s[4][4], c2s[4][4];
    #pragma unroll
    for (int t = 0; t < 4; ++t)
    #pragma unroll
    for (int r = 0; r < 4; ++r){ c0s[t][r]=0.f; c1s[t][r]=0.f; c2s[t][r]=0.f; }
    #pragma unroll
    for (int u = 0; u < 4; ++u){
        uint4 Bh = *(const uint4*)(wsu + WS_CFRAG + ((u*2+0)*64 + lane)*4);
        uint4 Bl = *(const uint4*)(wsu + WS_CFRAG + ((u*2+1)*64 + lane)*4);
        float beff = ws[WS_CBEFF + u*16 + ncol];
        float wd   = ws[WS_WD    + u*16 + ncol];
        float w2a  = ws[WS_W2C0  + u*16 + ncol];
        float w2b  = ws[WS_W2C1  + u*16 + ncol];
        float w2c  = ws[WS_W2C2  + u*16 + ncol];
        #pragma unroll
        for (int t = 0; t < 4; ++t){
            f32x4 acc = {0.f,0.f,0.f,0.f};
            acc = mfma_bf16(Ah[t], Bh, acc);
            acc = mfma_bf16(Ah[t], Bl, acc);
            acc = mfma_bf16(Al[t], Bh, acc);
            #pragma unroll
            for (int r = 0; r < 4; ++r){
                float a = fmaf(dens[t][r], wd, acc[r] + beff);
                a = fmaxf(a, 0.0f);
                c0s[t][r] = fmaf(a, w2a, c0s[t][r]);
                c1s[t][r] = fmaf(a, w2b, c1s[t][r]);
                c2s[t][r] = fmaf(a, w2c, c2s[t][r]);
            }
        }
    }
    #pragma unroll
    for (int m = 1; m < 16; m <<= 1){
        #pragma unroll
        for (int t = 0; t < 4; ++t)
        #pragma unroll
        for (int r = 0; r < 4; ++r){
            c0s[t][r] += __shfl_xor(c0s[t][r], m, 64);
            c1s[t][r] += __shfl_xor(c1s[t][r], m, 64);
            c2s[t][r] += __shfl_xor(c2s[t][r], m, 64);
        }
    }

    // ---- select own output point and store ----
    const float mc0 = ws[WS_MISC2 + 1];
    const float mc1 = ws[WS_MISC2 + 2];
    const float mc2 = ws[WS_MISC2 + 3];
    const int tsel = lane & 3;
    const int rsel = (lane >> 2) & 3;
    float od = 0.f, o0 = 0.f, o1 = 0.f, o2 = 0.f;
    #pragma unroll
    for (int t = 0; t < 4; ++t)
    #pragma unroll
    for (int r = 0; r < 4; ++r){
        bool msk = (t == tsel) && (r == rsel);
        od = msk ? dens[t][r] : od;
        o0 = msk ? c0s[t][r]  : o0;
        o1 = msk ? c1s[t][r]  : o1;
        o2 = msk ? c2s[t][r]  : o2;
    }
    const int q   = tsel*16 + (lane >> 4)*4 + rsel;
    const int idx = base + q;
    if (idx < N){
        out[idx] = od;
        float* oc = out + N;
        oc[3*idx + 0] = fast_sigmoid(o0 + mc0);
        oc[3*idx + 1] = fast_sigmoid(o1 + mc1);
        oc[3*idx + 2] = fast_sigmoid(o2 + mc2);
    }
}

extern "C" void kernel_launch(void* const* d_in, const int* in_sizes, int n_in,
                              void* d_out, int out_size, void* d_ws, size_t ws_size,
                              hipStream_t stream)
{
    const float* p             = (const float*)d_in[0];
    const float* initial_state = (const float*)d_in[1];
    const float* dyn_w1        = (const float*)d_in[2];
    const float* dyn_b1        = (const float*)d_in[3];
    const float* dyn_w2        = (const float*)d_in[4];
    const float* dyn_b2        = (const float*)d_in[5];
    const float* coupling      = (const float*)d_in[6];
    const float* damping       = (const float*)d_in[7];
    const float* interaction   = (const float*)d_in[8];
    const float* summ_w        = (const float*)d_in[9];
    const float* summ_b        = (const float*)d_in[10];
    const float* fq_w1         = (const float*)d_in[11];
    const float* fq_b1         = (const float*)d_in[12];
    const float* fq_w2         = (const float*)d_in[13];
    const float* fq_b2         = (const float*)d_in[14];
    const float* col_w1        = (const float*)d_in[15];
    const float* col_b1        = (const float*)d_in[16];
    const float* col_w2        = (const float*)d_in[17];
    const float* col_b2        = (const float*)d_in[18];
    const int*   tP            = (const int*)d_in[19];

    float* ws  = (float*)d_ws;
    float* out = (float*)d_out;
    const int N = in_sizes[0] / 3;

    hipLaunchKernelGGL(blob_sim_kernel, dim3(1), dim3(256), 0, stream,
                       initial_state, dyn_w1, dyn_b1, dyn_w2, dyn_b2,
                       coupling, damping, interaction, summ_w, summ_b,
                       fq_w1, fq_b1, fq_w2, fq_b2,
                       col_w1, col_b1, col_w2, col_b2, tP, ws);

    const int blocks = (N + 255) / 256;
    hipLaunchKernelGGL(field_kernel, dim3(blocks), dim3(256), 0, stream,
                       p, ws, out, N);
}